// Round 10
// baseline (71.697 us; speedup 1.0000x reference)
//
#include <hip/hip_runtime.h>

#define NPTS 8192
#define KNN  15
#define G    64
#define NC   (G * G)           // 4096 cells
#define TPB_A 1024
#define WPB  8
#define TPB  (WPB * 64)        // 512 threads
#define QPW  2                 // queries per wave (kernel B)
#define SEG  64

// d_ws layout (byte offsets)
#define WS_CS    16            // u16[4104] cell starts (4097 used)
#define WS_SIDX  8224          // u16[8192]: orig_idx | label<<13
#define WS_CRD   24608         // float2[8192] cell-sorted coords

__device__ __forceinline__ unsigned int bitonic_sort_u32(unsigned int v, int lane) {
#pragma unroll
  for (int k = 2; k <= 64; k <<= 1) {
#pragma unroll
    for (int j = k >> 1; j > 0; j >>= 1) {
      unsigned int o = __shfl_xor(v, j, 64);
      bool keep_min = ((lane & k) == 0) == ((lane & j) == 0);
      unsigned int lo = (v < o) ? v : o;
      unsigned int hi = (v < o) ? o : v;
      v = keep_min ? lo : hi;
    }
  }
  return v;
}

__device__ __forceinline__ unsigned long long bitonic_sort_u64(unsigned long long v, int lane) {
#pragma unroll
  for (int k = 2; k <= 64; k <<= 1) {
#pragma unroll
    for (int j = k >> 1; j > 0; j >>= 1) {
      unsigned long long o = __shfl_xor(v, j, 64);
      bool keep_min = ((lane & k) == 0) == ((lane & j) == 0);
      unsigned long long lo = (v < o) ? v : o;
      unsigned long long hi = (v < o) ? o : v;
      v = keep_min ? lo : hi;
    }
  }
  return v;
}

// Enumerate the contiguous sorted-array spans of Chebyshev ring r around
// (qcx,qcy); call body(s0,s1) for each. Lambda instead of macro: macro args
// split at top-level commas (braces don't protect), which broke round 9.
template <typename F>
__device__ __forceinline__ void ring_spans(int r, int qcx, int qcy,
                                           const unsigned short* cs_l, F&& body) {
  int x0 = qcx - r; if (x0 < 0) x0 = 0;
  int x1 = qcx + r; if (x1 > G - 1) x1 = G - 1;
  int ytop = qcy - r, ybot = qcy + r;
  if (ytop >= 0)               body(cs_l[ytop * G + x0], cs_l[ytop * G + x1 + 1]);
  if (r > 0 && ybot <= G - 1)  body(cs_l[ybot * G + x0], cs_l[ybot * G + x1 + 1]);
  if (r > 0) {
    int ry0 = ytop + 1; if (ry0 < 0) ry0 = 0;
    int ry1 = ybot - 1; if (ry1 > G - 1) ry1 = G - 1;
    int xl = qcx - r, xr = qcx + r;
    for (int ry = ry0; ry <= ry1; ++ry) {
      if (xl >= 0)     body(cs_l[ry * G + xl], cs_l[ry * G + xl + 1]);
      if (xr <= G - 1) body(cs_l[ry * G + xr], cs_l[ry * G + xr + 1]);
    }
  }
}

// ---------------- Kernel A: grid build (single block) ----------------
__global__ __launch_bounds__(TPB_A)
void build_kernel(const float* __restrict__ x, const int* __restrict__ y,
                  unsigned char* __restrict__ ws) {
  __shared__ unsigned int hist[NC];     // counts -> next-free
  __shared__ unsigned int tsum[TPB_A];
  __shared__ float rb[64];              // per-wave bbox partials
  __shared__ float hdr[4];

  const int t = threadIdx.x;
  const int lane = t & 63, wv = t >> 6;

  float px[8], py[8];
  float mnx = 3e38f, mxx = -3e38f, mny = 3e38f, mxy = -3e38f;
#pragma unroll
  for (int i = 0; i < 8; ++i) {
    float2 p = ((const float2*)x)[t + i * TPB_A];
    px[i] = p.x; py[i] = p.y;
    mnx = fminf(mnx, p.x); mxx = fmaxf(mxx, p.x);
    mny = fminf(mny, p.y); mxy = fmaxf(mxy, p.y);
  }
#pragma unroll
  for (int j = 32; j >= 1; j >>= 1) {
    mnx = fminf(mnx, __shfl_xor(mnx, j, 64));
    mxx = fmaxf(mxx, __shfl_xor(mxx, j, 64));
    mny = fminf(mny, __shfl_xor(mny, j, 64));
    mxy = fmaxf(mxy, __shfl_xor(mxy, j, 64));
  }
  if (lane == 0) { rb[wv] = mnx; rb[16 + wv] = mxx; rb[32 + wv] = mny; rb[48 + wv] = mxy; }
  for (int c = t; c < NC; c += TPB_A) hist[c] = 0;
  __syncthreads();
  if (t == 0) {
    float a = rb[0], b = rb[16], c2 = rb[32], d = rb[48];
    for (int i = 1; i < 16; ++i) {
      a = fminf(a, rb[i]); b = fmaxf(b, rb[16 + i]);
      c2 = fminf(c2, rb[32 + i]); d = fmaxf(d, rb[48 + i]);
    }
    float sp = fmaxf(b - a, d - c2) * (1.0f + 1e-6f) + 1e-6f;   // square cells
    hdr[0] = a; hdr[1] = c2; hdr[2] = (float)G / sp; hdr[3] = sp / (float)G;
    float* h = (float*)ws; h[0] = hdr[0]; h[1] = hdr[1]; h[2] = hdr[2]; h[3] = hdr[3];
  }
  __syncthreads();
  const float xmin = hdr[0], ymin = hdr[1], invw = hdr[2];

  int cell[8];
#pragma unroll
  for (int i = 0; i < 8; ++i) {
    int cx = (int)((px[i] - xmin) * invw); cx = cx < 0 ? 0 : (cx > G - 1 ? G - 1 : cx);
    int cy = (int)((py[i] - ymin) * invw); cy = cy < 0 ? 0 : (cy > G - 1 ? G - 1 : cy);
    cell[i] = cy * G + cx;
    atomicAdd(&hist[cell[i]], 1u);
  }
  __syncthreads();

  unsigned int h0 = hist[4 * t], h1 = hist[4 * t + 1], h2 = hist[4 * t + 2], h3 = hist[4 * t + 3];
  unsigned int s = h0 + h1 + h2 + h3;
  tsum[t] = s;
  __syncthreads();
  for (int st = 1; st < TPB_A; st <<= 1) {
    unsigned int v = (t >= st) ? tsum[t - st] : 0u;
    __syncthreads();
    tsum[t] += v;
    __syncthreads();
  }
  unsigned int ex = tsum[t] - s;
  unsigned short* cs = (unsigned short*)(ws + WS_CS);
  cs[4 * t]     = (unsigned short)ex;
  cs[4 * t + 1] = (unsigned short)(ex + h0);
  cs[4 * t + 2] = (unsigned short)(ex + h0 + h1);
  cs[4 * t + 3] = (unsigned short)(ex + h0 + h1 + h2);
  if (t == 0) cs[NC] = (unsigned short)NPTS;
  hist[4 * t] = ex; hist[4 * t + 1] = ex + h0;
  hist[4 * t + 2] = ex + h0 + h1; hist[4 * t + 3] = ex + h0 + h1 + h2;
  __syncthreads();

  float2* crd = (float2*)(ws + WS_CRD);
  unsigned short* sidx = (unsigned short*)(ws + WS_SIDX);
#pragma unroll
  for (int i = 0; i < 8; ++i) {
    int idx = t + i * TPB_A;
    unsigned int pos = atomicAdd(&hist[cell[i]], 1u);
    crd[pos] = make_float2(px[i], py[i]);
    sidx[pos] = (unsigned short)(idx | ((y[idx] & 1) << 13));
  }
}

// ---------------- Kernel B: ring-pruned query ----------------
__global__ __launch_bounds__(TPB)
void query_kernel(const float* __restrict__ x,
                  const unsigned char* __restrict__ ws,
                  float* __restrict__ out) {
  __shared__ float2 crd_l[NPTS];               // 64 KB cell-sorted coords
  __shared__ unsigned short cs_l[NC + 8];      // 8.2 KB cell starts
  __shared__ unsigned int buf[WPB][SEG];       // 2 KB candidate positions

  const int t = threadIdx.x;
  const float4* g4 = (const float4*)(ws + WS_CRD);
#pragma unroll
  for (int i = t; i < NPTS / 2; i += TPB) ((float4*)crd_l)[i] = g4[i];
  const unsigned int* gcs = (const unsigned int*)(ws + WS_CS);
  for (int i = t; i < (NC + 8) / 2; i += TPB) ((unsigned int*)cs_l)[i] = gcs[i];
  __syncthreads();

  const float* hdr = (const float*)ws;
  const float xmin = hdr[0], ymin = hdr[1], invw = hdr[2], w = hdr[3];
  const unsigned short* gsidx = (const unsigned short*)(ws + WS_SIDX);

  const int wv = t >> 6, lane = t & 63;
  const unsigned long long lmask = (lane == 63) ? 0x7FFFFFFFFFFFFFFFull
                                                : ((1ull << lane) - 1ull);

  for (int qt = 0; qt < QPW; ++qt) {
    const int q = ((int)blockIdx.x * WPB + wv) * QPW + qt;
    const float2 xq = ((const float2*)x)[q];
    int qcx = (int)((xq.x - xmin) * invw); qcx = qcx < 0 ? 0 : (qcx > G - 1 ? G - 1 : qcx);
    int qcy = (int)((xq.y - ymin) * invw); qcy = qcy < 0 ? 0 : (qcy > G - 1 ? G - 1 : qcy);

    // ---- scan A: expand rings, per-lane round-robin min, ballot-certify ----
    float m = 3e38f;
    int C = 0, rmax = 0;
    for (int r = 0; r < 2 * G; ++r) {
      ring_spans(r, qcx, qcy, cs_l, [&](int s0, int s1) {
        int n = s1 - s0;
        int base = (lane - (C & 63)) & 63;        // round-robin lane balance
        int iters = (n + 63) >> 6;
        for (int it = 0; it < iters; ++it) {
          int jj2 = (it << 6) + base;
          bool act = jj2 < n;
          float2 pp = crd_l[s0 + (act ? jj2 : 0)];
          float dx = xq.x - pp.x;
          float dy = xq.y - pp.y;
          float d = __builtin_fmaf(dx, dx, dy * dy);
          if (act) m = fminf(m, d);
        }
        C += n;
      });
      bool full = (qcx - r <= 0) && (qcy - r <= 0) &&
                  (qcx + r >= G - 1) && (qcy + r >= G - 1);
      if (C >= 16) {
        float lb = fmaxf(0.0f, (float)r * w - 1e-4f);   // rings >r are >= lb away
        float LBs = lb * lb * (1.0f - 1e-5f) - 1e-30f;  // fp32/fp64 safety shrink
        unsigned long long bl = __ballot(m <= LBs);
        if (__popcll(bl) >= 16) { rmax = r; break; }    // >=16 pts closer than any unscanned
      }
      if (full) { rmax = r; break; }
    }

    // T16 = 16th-smallest lane-min (>=16 distinct pts <= T16, >=15 non-self)
    unsigned int srt = bitonic_sort_u32(__float_as_uint(m), lane);
    const float T16 = __uint_as_float(__shfl(srt, KNN, 64));
    const float T = T16 * (1.0f + 1e-5f) + 1e-30f;      // covers fp32 eval noise

    // ---- scan B: collect candidate positions with d32 <= T ----
    int cnt = 0;
    for (int r = 0; r <= rmax; ++r) {
      ring_spans(r, qcx, qcy, cs_l, [&](int s0, int s1) {
        int n = s1 - s0;
        int iters = (n + 63) >> 6;
        for (int it = 0; it < iters; ++it) {
          int jj2 = (it << 6) + lane;
          bool act = jj2 < n;
          float2 pp = crd_l[s0 + (act ? jj2 : 0)];
          float dx = xq.x - pp.x;
          float dy = xq.y - pp.y;
          float d = __builtin_fmaf(dx, dx, dy * dy);
          bool c = act && (d <= T);
          unsigned long long k = __ballot(c);
          if (c) {
            int o = cnt + __popcll(k & lmask);
            if (o < SEG) buf[wv][o] = (unsigned int)(s0 + jj2);
          }
          cnt += __popcll(k);
        }
      });
    }

    // ---- exact fp64 re-rank of ~17 survivors, sort, vote ----
    int C2 = (cnt > SEG) ? SEG : cnt;
    unsigned long long kv = ~0ull;
    if (lane < C2) {
      int pos = (int)buf[wv][lane];
      float2 pj = crd_l[pos];                         // exact fp32 originals
      unsigned int si = gsidx[pos];
      int jj = (int)(si & 0x1FFFu);
      unsigned long long lbl = (si >> 13) & 1u;
      double dx = (double)xq.x - (double)pj.x;        // exact fp32->fp64
      double dy = (double)xq.y - (double)pj.y;
      double dd = dx * dx + dy * dy;                  // rel err ~1e-16
      kv = ((unsigned long long)__double_as_longlong(dd) & ~0x3FFFull) |
           ((unsigned long long)jj << 1) | lbl;       // tie-break: lower orig idx
      if (jj == q) kv = ~0ull;                        // drop self
    }
    kv = bitonic_sort_u64(kv, lane);
    unsigned long long vm = __ballot((lane < KNN) && (kv & 1ull));
    if (lane == 0) out[q] = (__popcll(vm) >= 8) ? 1.0f : 0.0f;   // sum > 7.5
  }
}

extern "C" void kernel_launch(void* const* d_in, const int* in_sizes, int n_in,
                              void* d_out, int out_size, void* d_ws, size_t ws_size,
                              hipStream_t stream) {
  const float* x = (const float*)d_in[0];
  const int* y = (const int*)d_in[1];
  float* out = (float*)d_out;
  unsigned char* ws = (unsigned char*)d_ws;
  hipLaunchKernelGGL(build_kernel, dim3(1), dim3(TPB_A), 0, stream, x, y, ws);
  hipLaunchKernelGGL(query_kernel, dim3(NPTS / (WPB * QPW)), dim3(TPB), 0, stream,
                     x, ws, out);
}

// Round 12
// 51.900 us; speedup vs baseline: 1.3814x; 1.3814x over previous
//
#include <hip/hip_runtime.h>

#define NPTS 8192
#define KNN  15
#define G    64
#define NC   (G * G)           // 4096 cells
#define TPB_A 1024
#define WPB  8
#define TPB  (WPB * 64)        // 512 threads, 1 query per wave
#define SEG  64

// d_ws layout (byte offsets)
#define WS_CS    16            // u16[4104] cell starts (4097 used)
#define WS_SIDX  8224          // u16[8192]: orig_idx | label<<13
#define WS_CRD   24608         // float2[8192] cell-sorted coords

__device__ __forceinline__ unsigned int bitonic_sort_u32(unsigned int v, int lane) {
#pragma unroll
  for (int k = 2; k <= 64; k <<= 1) {
#pragma unroll
    for (int j = k >> 1; j > 0; j >>= 1) {
      unsigned int o = __shfl_xor(v, j, 64);
      bool keep_min = ((lane & k) == 0) == ((lane & j) == 0);
      unsigned int lo = (v < o) ? v : o;
      unsigned int hi = (v < o) ? o : v;
      v = keep_min ? lo : hi;
    }
  }
  return v;
}

__device__ __forceinline__ unsigned long long bitonic_sort_u64(unsigned long long v, int lane) {
#pragma unroll
  for (int k = 2; k <= 64; k <<= 1) {
#pragma unroll
    for (int j = k >> 1; j > 0; j >>= 1) {
      unsigned long long o = __shfl_xor(v, j, 64);
      bool keep_min = ((lane & k) == 0) == ((lane & j) == 0);
      unsigned long long lo = (v < o) ? v : o;
      unsigned long long hi = (v < o) ? o : v;
      v = keep_min ? lo : hi;
    }
  }
  return v;
}

// ---------------- Kernel A: grid build (single block) ----------------
__global__ __launch_bounds__(TPB_A)
void build_kernel(const float* __restrict__ x, const int* __restrict__ y,
                  unsigned char* __restrict__ ws) {
  __shared__ unsigned int hist[NC];     // counts -> next-free
  __shared__ float rb[64];              // per-wave bbox partials
  __shared__ float hdr[4];
  __shared__ unsigned int wsum[16];     // per-wave scan totals

  const int t = threadIdx.x;
  const int lane = t & 63, wv = t >> 6;

  float px[8], py[8];
  float mnx = 3e38f, mxx = -3e38f, mny = 3e38f, mxy = -3e38f;
#pragma unroll
  for (int i = 0; i < 8; ++i) {
    float2 p = ((const float2*)x)[t + i * TPB_A];
    px[i] = p.x; py[i] = p.y;
    mnx = fminf(mnx, p.x); mxx = fmaxf(mxx, p.x);
    mny = fminf(mny, p.y); mxy = fmaxf(mxy, p.y);
  }
#pragma unroll
  for (int j = 32; j >= 1; j >>= 1) {
    mnx = fminf(mnx, __shfl_xor(mnx, j, 64));
    mxx = fmaxf(mxx, __shfl_xor(mxx, j, 64));
    mny = fminf(mny, __shfl_xor(mny, j, 64));
    mxy = fmaxf(mxy, __shfl_xor(mxy, j, 64));
  }
  if (lane == 0) { rb[wv] = mnx; rb[16 + wv] = mxx; rb[32 + wv] = mny; rb[48 + wv] = mxy; }
  for (int c = t; c < NC; c += TPB_A) hist[c] = 0;
  __syncthreads();
  if (t == 0) {
    float a = rb[0], b = rb[16], c2 = rb[32], d = rb[48];
    for (int i = 1; i < 16; ++i) {
      a = fminf(a, rb[i]); b = fmaxf(b, rb[16 + i]);
      c2 = fminf(c2, rb[32 + i]); d = fmaxf(d, rb[48 + i]);
    }
    float sp = fmaxf(b - a, d - c2) * (1.0f + 1e-6f) + 1e-6f;   // square cells
    hdr[0] = a; hdr[1] = c2; hdr[2] = (float)G / sp; hdr[3] = sp / (float)G;
    float* h = (float*)ws; h[0] = hdr[0]; h[1] = hdr[1]; h[2] = hdr[2]; h[3] = hdr[3];
  }
  __syncthreads();
  const float xmin = hdr[0], ymin = hdr[1], invw = hdr[2];

  int cell[8];
#pragma unroll
  for (int i = 0; i < 8; ++i) {
    int cx = (int)((px[i] - xmin) * invw); cx = cx < 0 ? 0 : (cx > G - 1 ? G - 1 : cx);
    int cy = (int)((py[i] - ymin) * invw); cy = cy < 0 ? 0 : (cy > G - 1 ? G - 1 : cy);
    cell[i] = cy * G + cx;
    atomicAdd(&hist[cell[i]], 1u);
  }
  __syncthreads();

  // 3-barrier prefix scan over 4096 cell counts (4 cells per thread)
  unsigned int h0 = hist[4 * t], h1 = hist[4 * t + 1], h2 = hist[4 * t + 2], h3 = hist[4 * t + 3];
  unsigned int s = h0 + h1 + h2 + h3;
  unsigned int ps = s;                                // inclusive wave scan
#pragma unroll
  for (int j = 1; j < 64; j <<= 1) {
    unsigned int o = __shfl_up(ps, j, 64);
    if (lane >= j) ps += o;
  }
  if (lane == 63) wsum[wv] = ps;
  __syncthreads();
  if (t == 0) {
    unsigned int a = 0;
    for (int i = 0; i < 16; ++i) { unsigned int v = wsum[i]; wsum[i] = a; a += v; }
  }
  __syncthreads();
  unsigned int ex = wsum[wv] + ps - s;                // exclusive prefix, this thread

  unsigned short* cs = (unsigned short*)(ws + WS_CS);
  cs[4 * t]     = (unsigned short)ex;
  cs[4 * t + 1] = (unsigned short)(ex + h0);
  cs[4 * t + 2] = (unsigned short)(ex + h0 + h1);
  cs[4 * t + 3] = (unsigned short)(ex + h0 + h1 + h2);
  if (t == 0) cs[NC] = (unsigned short)NPTS;
  hist[4 * t] = ex; hist[4 * t + 1] = ex + h0;
  hist[4 * t + 2] = ex + h0 + h1; hist[4 * t + 3] = ex + h0 + h1 + h2;
  __syncthreads();

  float2* crd = (float2*)(ws + WS_CRD);
  unsigned short* sidx = (unsigned short*)(ws + WS_SIDX);
#pragma unroll
  for (int i = 0; i < 8; ++i) {
    int idx = t + i * TPB_A;
    unsigned int pos = atomicAdd(&hist[cell[i]], 1u);
    crd[pos] = make_float2(px[i], py[i]);
    sidx[pos] = (unsigned short)(idx | ((y[idx] & 1) << 13));
  }
}

// ---------------- Kernel B: row-span point-parallel square-pruned query ----------------
__global__ __launch_bounds__(TPB)
void query_kernel(const float* __restrict__ x,
                  const unsigned char* __restrict__ ws,
                  float* __restrict__ out) {
  __shared__ float2 crd_l[NPTS];               // 64 KB cell-sorted coords
  __shared__ unsigned short cs_l[NC + 8];      // 8.2 KB cell starts
  __shared__ unsigned int buf[WPB][SEG];       // 2 KB candidate positions

  const int t = threadIdx.x;
  const float4* g4 = (const float4*)(ws + WS_CRD);
#pragma unroll
  for (int i = t; i < NPTS / 2; i += TPB) ((float4*)crd_l)[i] = g4[i];
  const unsigned int* gcs = (const unsigned int*)(ws + WS_CS);
  for (int i = t; i < (NC + 8) / 2; i += TPB) ((unsigned int*)cs_l)[i] = gcs[i];
  __syncthreads();

  const float* hdr = (const float*)ws;
  const float xmin = hdr[0], ymin = hdr[1], invw = hdr[2], w = hdr[3];
  const unsigned short* gsidx = (const unsigned short*)(ws + WS_SIDX);

  const int wv = t >> 6, lane = t & 63;
  const unsigned long long lmask = (1ull << lane) - 1ull;   // lane 63: 0x7FFF... (shift<64, ok)

  const int q = (int)blockIdx.x * WPB + wv;          // 1 query per wave
  const float2 xq = ((const float2*)x)[q];
  int qcx = (int)((xq.x - xmin) * invw); qcx = qcx < 0 ? 0 : (qcx > G - 1 ? G - 1 : qcx);
  int qcy = (int)((xq.y - ymin) * invw); qcy = qcy < 0 ? 0 : (qcy > G - 1 ? G - 1 : qcy);

  // ---- scan A: square ladder; ROW-SPAN point-parallel; round-robin lanes ----
  // Point-round-robin partition (R2-R10 proven): consecutive points in the
  // cell-sorted array go to consecutive lanes, so clustered top-16 points
  // spread across ~16 lanes and T16 stays tight. (R11's lane-per-CELL
  // partition put the whole top-16 in 1-3 lanes; T16 blew up; SEG overflowed.)
  // Certification (R10, absmax 0): all in-grid cells at Chebyshev distance
  // <= r scanned => unscanned points are >= r*w away. >=16 lanes (distinct
  // points) with min <= (r*w-1e-4)^2*(1-1e-5) => true top-16 inside block.
  float m = 3e38f;
  int bx0 = 0, bx1 = 0, by0 = 0, by1 = 0;
  for (int lvl = 0; lvl < 5; ++lvl) {
    const int r = (lvl == 0) ? 3 : (lvl == 1) ? 7 : (lvl == 2) ? 15 : (lvl == 3) ? 31 : 63;
    bx0 = qcx - r; if (bx0 < 0) bx0 = 0;
    bx1 = qcx + r; if (bx1 > G - 1) bx1 = G - 1;
    by0 = qcy - r; if (by0 < 0) by0 = 0;
    by1 = qcy + r; if (by1 > G - 1) by1 = G - 1;
    m = 3e38f;                                   // rescan block from scratch
    int C = 0;
    for (int ry = by0; ry <= by1; ++ry) {        // one contiguous span per row
      int s0 = (int)cs_l[ry * G + bx0];
      int s1 = (int)cs_l[ry * G + bx1 + 1];
      int n = s1 - s0;
      int base = (lane - C) & 63;                // round-robin continuation
      int iters = (n + 63) >> 6;
      for (int it = 0; it < iters; ++it) {
        int j = (it << 6) + base;
        bool a = j < n;
        float2 pp = crd_l[a ? s0 + j : 0];
        float dx = xq.x - pp.x, dy = xq.y - pp.y;
        float d = __builtin_fmaf(dx, dx, dy * dy);
        if (a) m = fminf(m, d);
      }
      C += n;
    }
    bool fullgrid = (bx0 == 0) && (by0 == 0) && (bx1 == G - 1) && (by1 == G - 1);
    float lb = (float)r * w - 1e-4f; if (lb < 0.0f) lb = 0.0f;
    float LBs = lb * lb * (1.0f - 1e-5f) - 1e-30f;
    if (fullgrid || __popcll(__ballot(m <= LBs)) >= 16) break;
  }

  // T16 = 16th-smallest lane-min (>=16 distinct pts <= T16, >=15 non-self)
  unsigned int srt = bitonic_sort_u32(__float_as_uint(m), lane);
  const float T16 = __uint_as_float(__shfl(srt, KNN, 64));
  const float T = T16 * (1.0f + 1e-5f) + 1e-30f;      // covers fp32 eval noise

  // ---- scan B: collect positions with d32 <= T over the certified block ----
  int cnt = 0;
  for (int ry = by0; ry <= by1; ++ry) {
    int s0 = (int)cs_l[ry * G + bx0];
    int s1 = (int)cs_l[ry * G + bx1 + 1];
    int n = s1 - s0;
    int iters = (n + 63) >> 6;
    for (int it = 0; it < iters; ++it) {
      int j = (it << 6) + lane;
      bool a = j < n;
      float2 pp = crd_l[a ? s0 + j : 0];
      float dx = xq.x - pp.x, dy = xq.y - pp.y;
      float d = __builtin_fmaf(dx, dx, dy * dy);
      bool c = a && (d <= T);
      unsigned long long kb = __ballot(c);
      if (c) {
        int o = cnt + __popcll(kb & lmask);
        if (o < SEG) buf[wv][o] = (unsigned int)(s0 + j);
      }
      cnt += __popcll(kb);
    }
  }

  // ---- exact fp64 re-rank of ~17-35 survivors, sort, vote ----
  int C2 = (cnt > SEG) ? SEG : cnt;
  unsigned long long kv = ~0ull;
  if (lane < C2) {
    int pos = (int)buf[wv][lane];
    float2 pj = crd_l[pos];                         // exact fp32 originals
    unsigned int si = gsidx[pos];
    int jj = (int)(si & 0x1FFFu);
    unsigned long long lbl = (si >> 13) & 1u;
    double dx = (double)xq.x - (double)pj.x;        // exact fp32->fp64
    double dy = (double)xq.y - (double)pj.y;
    double dd = dx * dx + dy * dy;                  // rel err ~1e-16
    kv = ((unsigned long long)__double_as_longlong(dd) & ~0x3FFFull) |
         ((unsigned long long)jj << 1) | lbl;       // tie-break: lower orig idx
    if (jj == q) kv = ~0ull;                        // drop self
  }
  kv = bitonic_sort_u64(kv, lane);
  unsigned long long vm = __ballot((lane < KNN) && (kv & 1ull));
  if (lane == 0) out[q] = (__popcll(vm) >= 8) ? 1.0f : 0.0f;   // sum > 7.5
}

extern "C" void kernel_launch(void* const* d_in, const int* in_sizes, int n_in,
                              void* d_out, int out_size, void* d_ws, size_t ws_size,
                              hipStream_t stream) {
  const float* x = (const float*)d_in[0];
  const int* y = (const int*)d_in[1];
  float* out = (float*)d_out;
  unsigned char* ws = (unsigned char*)d_ws;
  hipLaunchKernelGGL(build_kernel, dim3(1), dim3(TPB_A), 0, stream, x, y, ws);
  hipLaunchKernelGGL(query_kernel, dim3(NPTS / WPB), dim3(TPB), 0, stream,
                     x, ws, out);
}